// Round 5
// baseline (1243.136 us; speedup 1.0000x reference)
//
#include <hip/hip_runtime.h>

#define B_ 8
#define C_ 256
#define H_ 96
#define W_ 128
#define HW_ (H_*W_)
#define PATCH_ 21
#define MAXD_ 20
#define P2_ 168                 // staged positions per dy row
#define NBLK_ (B_*24*11)        // 2112 blocks of 4 waves (4 h each)

typedef __fp16 half2_t __attribute__((ext_vector_type(2)));
typedef __fp16 h8_t    __attribute__((ext_vector_type(8)));
typedef float  f4_t    __attribute__((ext_vector_type(4)));

__device__ __forceinline__ float fdot2f(half2_t a, half2_t b, float c) {
  return __builtin_amdgcn_fdot2(a, b, c, false);
}
__device__ __forceinline__ int swz(int pos) { return pos ^ ((pos >> 3) & 7); }

__global__ __launch_bounds__(256, 4) void corr_kernel(
    const float* __restrict__ in1,
    const float* __restrict__ in2,
    float* __restrict__ out) {
  // 4 independent per-wave regions; no cross-wave sharing -> no __syncthreads
  __shared__ h8_t lds[4 * 2 * P2_];

  const int tid  = threadIdx.x;
  const int wid  = tid >> 6;         // wave -> which h of the 4
  const int lane = tid & 63;
  const int l    = lane & 15;        // w-lane: w0 = 8*l covers W=128
  const int q    = (lane >> 4) & 1;  // dx half: 0 -> dx 0..10, 1 -> dx 11..20
  const int gdy  = lane >> 5;        // dy sub-index within wave's pair

  // XCD-chunked swizzle: 2112 = 8 * 264; each XCD chunk = one batch image
  int bid = blockIdx.x;
  bid = (bid & 7) * (NBLK_ / 8) + (bid >> 3);
  const int dyb = bid % 11;
  const int hg  = (bid / 11) % 24;
  const int b   = bid / (11 * 24);
  const int h   = hg * 4 + wid;

  const int dy   = 2 * dyb + gdy;    // 0..21 (21 = pad, store-masked)
  const int w0   = 8 * l;
  const int rel0 = 20 * q;           // q=1 computes dx=10..20, stores 11..20

  float acc[8][11];
#pragma unroll
  for (int j = 0; j < 8; ++j)
#pragma unroll
    for (int i = 0; i < 11; ++i) acc[j][i] = 0.f;

  const int wbase   = wid * (2 * P2_);
  const int ldsbase = wbase + gdy * P2_;

  for (int c0 = 0; c0 < C_; c0 += 8) {
    // ---- stage this wave's 2 dy rows x 168 pos x 8 ch (f32 -> packed f16) ----
#pragma unroll
    for (int s = lane; s < 2 * P2_; s += 64) {
      const int dyidx = (s >= P2_) ? 1 : 0;
      const int pos = s - P2_ * dyidx;
      const int h2 = h + 2 * (2 * dyb + dyidx) - MAXD_;
      const int w2 = pos - MAXD_;
      const bool v = ((unsigned)h2 < (unsigned)H_) && ((unsigned)w2 < (unsigned)W_);
      float f[8];
      if (v) {
        const float* bp = in2 + ((size_t)(b * C_ + c0) * H_ + h2) * W_ + w2;
#pragma unroll
        for (int j = 0; j < 8; ++j) f[j] = bp[(size_t)j * HW_];
      } else {
#pragma unroll
        for (int j = 0; j < 8; ++j) f[j] = 0.f;
      }
      h8_t pk;
#pragma unroll
      for (int jj = 0; jj < 4; ++jj) {
        half2_t p2 = __builtin_amdgcn_cvt_pkrtz(f[2 * jj], f[2 * jj + 1]);
        pk[2 * jj]     = p2.x;
        pk[2 * jj + 1] = p2.y;
      }
      lds[wbase + dyidx * P2_ + swz(pos)] = pk;
    }

    // ---- A fragments: 8 consecutive w, 8 ch, packed to half2 pairs ----
    const float* a_base = in1 + ((size_t)(b * C_ + c0) * H_ + h) * W_ + w0;
    half2_t a2[8][4];
#pragma unroll
    for (int jj = 0; jj < 4; ++jj) {
      f4_t lo0 = *(const f4_t*)(a_base + (size_t)(2 * jj) * HW_);
      f4_t lo1 = *(const f4_t*)(a_base + (size_t)(2 * jj) * HW_ + 4);
      f4_t hi0 = *(const f4_t*)(a_base + (size_t)(2 * jj + 1) * HW_);
      f4_t hi1 = *(const f4_t*)(a_base + (size_t)(2 * jj + 1) * HW_ + 4);
#pragma unroll
      for (int j = 0; j < 4; ++j) {
        a2[j][jj]     = __builtin_amdgcn_cvt_pkrtz(lo0[j], hi0[j]);
        a2[j + 4][jj] = __builtin_amdgcn_cvt_pkrtz(lo1[j], hi1[j]);
      }
    }

    // ---- preload 8-position register window (slot = rel & 7) ----
    // (in-order DS per wave: these reads see this chunk's writes, no barrier)
    h8_t wv[8];
#pragma unroll
    for (int k = 0; k < 8; ++k)
      wv[k] = lds[ldsbase + swz(w0 + rel0 + k)];

    // ---- 11 dx steps: 32 dot2 each, slide window by 2 ----
#pragma unroll
    for (int i = 0; i < 11; ++i) {
#pragma unroll
      for (int j = 0; j < 8; ++j) {
        const h8_t wj = wv[(2 * i + j) & 7];
#pragma unroll
        for (int jj = 0; jj < 4; ++jj) {
          half2_t bb;
          bb.x = wj[2 * jj];
          bb.y = wj[2 * jj + 1];
          acc[j][i] = fdot2f(a2[j][jj], bb, acc[j][i]);
        }
      }
      if (i < 10) {
        wv[(2 * i + 8) & 7] = lds[ldsbase + swz(w0 + rel0 + 2 * i + 8)];
        wv[(2 * i + 9) & 7] = lds[ldsbase + swz(w0 + rel0 + 2 * i + 9)];
      }
    }
  }

  // ---- epilogue ----
  if (dy < PATCH_) {
    const float s = 1.f / (float)C_;
#pragma unroll
    for (int i = 0; i < 11; ++i) {
      if (q && i == 0) continue;          // q=1's i=0 (dx=10) is duplicate work
      const int dx = 10 * q + i;
      float* ob = out + ((size_t)(b * (PATCH_ * PATCH_) + dy * PATCH_ + dx) * H_ + h) * W_ + w0;
      f4_t v0, v1;
#pragma unroll
      for (int j = 0; j < 4; ++j) {
        float x = acc[j][i] * s;
        v0[j] = (x >= 0.f) ? x : 0.1f * x;
        float y = acc[j + 4][i] * s;
        v1[j] = (y >= 0.f) ? y : 0.1f * y;
      }
      *(f4_t*)ob = v0;
      *(f4_t*)(ob + 4) = v1;
    }
  }
}

extern "C" void kernel_launch(void* const* d_in, const int* in_sizes, int n_in,
                              void* d_out, int out_size, void* d_ws, size_t ws_size,
                              hipStream_t stream) {
  (void)in_sizes; (void)n_in; (void)d_ws; (void)ws_size; (void)out_size;
  const float* in1 = (const float*)d_in[0];
  const float* in2 = (const float*)d_in[1];
  float* out = (float*)d_out;
  corr_kernel<<<dim3(NBLK_), dim3(256), 0, stream>>>(in1, in2, out);
}

// Round 6
// 494.094 us; speedup vs baseline: 2.5160x; 2.5160x over previous
//
#include <hip/hip_runtime.h>

#define B_ 8
#define C_ 256
#define H_ 96
#define W_ 128
#define HW_ (H_*W_)
#define PATCH_ 21
#define MAXD_ 20
#define P2_ 168                 // staged positions per dy row
#define NBLK_ (B_*24*11)        // 2112 blocks of 4 waves (4 h each)

typedef __fp16 half2_t __attribute__((ext_vector_type(2)));
typedef __fp16 h8_t    __attribute__((ext_vector_type(8)));
typedef float  f4_t    __attribute__((ext_vector_type(4)));

__device__ __forceinline__ float fdot2f(half2_t a, half2_t b, float c) {
  return __builtin_amdgcn_fdot2(a, b, c, false);
}
__device__ __forceinline__ int swz(int pos) { return pos ^ ((pos >> 3) & 7); }

__global__ __launch_bounds__(256, 2) void corr_kernel(
    const float* __restrict__ in1,
    const float* __restrict__ in2,
    float* __restrict__ out) {
  // 4 independent per-wave regions; no cross-wave sharing -> no __syncthreads
  __shared__ h8_t lds[4 * 2 * P2_];

  const int tid  = threadIdx.x;
  const int wid  = tid >> 6;         // wave -> which h of the 4
  const int lane = tid & 63;
  const int l    = lane & 15;        // w-lane: w0 = 8*l covers W=128
  const int q    = (lane >> 4) & 1;  // dx half: 0 -> dx 0..10, 1 -> dx 11..20
  const int gdy  = lane >> 5;        // dy sub-index within wave's pair

  // XCD-chunked swizzle: 2112 = 8 * 264; each XCD chunk = one batch image
  int bid = blockIdx.x;
  bid = (bid & 7) * (NBLK_ / 8) + (bid >> 3);
  const int dyb = bid % 11;
  const int hg  = (bid / 11) % 24;
  const int b   = bid / (11 * 24);
  const int h   = hg * 4 + wid;

  const int dy   = 2 * dyb + gdy;    // 0..21 (21 = pad, store-masked)
  const int w0   = 8 * l;
  const int rel0 = 20 * q;           // q=1 computes dx=10..20, stores 11..20

  float acc[8][11];
#pragma unroll
  for (int j = 0; j < 8; ++j)
#pragma unroll
    for (int i = 0; i < 11; ++i) acc[j][i] = 0.f;

  const int wbase   = wid * (2 * P2_);
  const int ldsbase = wbase + gdy * P2_;

  for (int c0 = 0; c0 < C_; c0 += 8) {
    // ---- stage this wave's 2 dy rows x 168 pos x 8 ch (f32 -> packed f16) ----
#pragma unroll
    for (int s = lane; s < 2 * P2_; s += 64) {
      const int dyidx = (s >= P2_) ? 1 : 0;
      const int pos = s - P2_ * dyidx;
      const int h2 = h + 2 * (2 * dyb + dyidx) - MAXD_;
      const int w2 = pos - MAXD_;
      const bool v = ((unsigned)h2 < (unsigned)H_) && ((unsigned)w2 < (unsigned)W_);
      float f[8];
      if (v) {
        const float* bp = in2 + ((size_t)(b * C_ + c0) * H_ + h2) * W_ + w2;
#pragma unroll
        for (int j = 0; j < 8; ++j) f[j] = bp[(size_t)j * HW_];
      } else {
#pragma unroll
        for (int j = 0; j < 8; ++j) f[j] = 0.f;
      }
      h8_t pk;
#pragma unroll
      for (int jj = 0; jj < 4; ++jj) {
        half2_t p2 = __builtin_amdgcn_cvt_pkrtz(f[2 * jj], f[2 * jj + 1]);
        pk[2 * jj]     = p2.x;
        pk[2 * jj + 1] = p2.y;
      }
      lds[wbase + dyidx * P2_ + swz(pos)] = pk;
    }

    // ---- A fragments: 8 consecutive w, 8 ch, packed to half2 pairs ----
    const float* a_base = in1 + ((size_t)(b * C_ + c0) * H_ + h) * W_ + w0;
    half2_t a2[8][4];
#pragma unroll
    for (int jj = 0; jj < 4; ++jj) {
      f4_t lo0 = *(const f4_t*)(a_base + (size_t)(2 * jj) * HW_);
      f4_t lo1 = *(const f4_t*)(a_base + (size_t)(2 * jj) * HW_ + 4);
      f4_t hi0 = *(const f4_t*)(a_base + (size_t)(2 * jj + 1) * HW_);
      f4_t hi1 = *(const f4_t*)(a_base + (size_t)(2 * jj + 1) * HW_ + 4);
#pragma unroll
      for (int j = 0; j < 4; ++j) {
        a2[j][jj]     = __builtin_amdgcn_cvt_pkrtz(lo0[j], hi0[j]);
        a2[j + 4][jj] = __builtin_amdgcn_cvt_pkrtz(lo1[j], hi1[j]);
      }
    }

    // ---- preload 8-position register window (slot = rel & 7) ----
    // (in-order DS per wave: these reads see this chunk's writes, no barrier)
    h8_t wv[8];
#pragma unroll
    for (int k = 0; k < 8; ++k)
      wv[k] = lds[ldsbase + swz(w0 + rel0 + k)];

    // ---- 11 dx steps: 32 dot2 each, slide window by 2 ----
#pragma unroll
    for (int i = 0; i < 11; ++i) {
#pragma unroll
      for (int j = 0; j < 8; ++j) {
        const h8_t wj = wv[(2 * i + j) & 7];
#pragma unroll
        for (int jj = 0; jj < 4; ++jj) {
          half2_t bb;
          bb.x = wj[2 * jj];
          bb.y = wj[2 * jj + 1];
          acc[j][i] = fdot2f(a2[j][jj], bb, acc[j][i]);
        }
      }
      if (i < 10) {
        wv[(2 * i + 8) & 7] = lds[ldsbase + swz(w0 + rel0 + 2 * i + 8)];
        wv[(2 * i + 9) & 7] = lds[ldsbase + swz(w0 + rel0 + 2 * i + 9)];
      }
    }
  }

  // ---- epilogue ----
  if (dy < PATCH_) {
    const float s = 1.f / (float)C_;
#pragma unroll
    for (int i = 0; i < 11; ++i) {
      if (q && i == 0) continue;          // q=1's i=0 (dx=10) is duplicate work
      const int dx = 10 * q + i;
      float* ob = out + ((size_t)(b * (PATCH_ * PATCH_) + dy * PATCH_ + dx) * H_ + h) * W_ + w0;
      f4_t v0, v1;
#pragma unroll
      for (int j = 0; j < 4; ++j) {
        float x = acc[j][i] * s;
        v0[j] = (x >= 0.f) ? x : 0.1f * x;
        float y = acc[j + 4][i] * s;
        v1[j] = (y >= 0.f) ? y : 0.1f * y;
      }
      *(f4_t*)ob = v0;
      *(f4_t*)(ob + 4) = v1;
    }
  }
}

extern "C" void kernel_launch(void* const* d_in, const int* in_sizes, int n_in,
                              void* d_out, int out_size, void* d_ws, size_t ws_size,
                              hipStream_t stream) {
  (void)in_sizes; (void)n_in; (void)d_ws; (void)ws_size; (void)out_size;
  const float* in1 = (const float*)d_in[0];
  const float* in2 = (const float*)d_in[1];
  float* out = (float*)d_out;
  corr_kernel<<<dim3(NBLK_), dim3(256), 0, stream>>>(in1, in2, out);
}

// Round 7
// 479.112 us; speedup vs baseline: 2.5947x; 1.0313x over previous
//
#include <hip/hip_runtime.h>

#define B_ 8
#define C_ 256
#define H_ 96
#define W_ 128
#define HW_ (H_*W_)
#define PATCH_ 21
#define MAXD_ 20
#define P2_ 168                  // staged positions per dy row
#define NBLK_ (B_*24*11)         // 2112 blocks of 4 waves (4 h each)
#define NGRAN_ (B_*32*H_*W_)     // 3,145,728 h8 granules per input
#define WS_NEED_ ((size_t)2 * (size_t)NGRAN_ * 16)

typedef __fp16 half2_t __attribute__((ext_vector_type(2)));
typedef __fp16 h8_t    __attribute__((ext_vector_type(8)));
typedef float  f4_t    __attribute__((ext_vector_type(4)));

__device__ __forceinline__ float fdot2f(half2_t a, half2_t b, float c) {
  return __builtin_amdgcn_fdot2(a, b, c, false);
}
__device__ __forceinline__ int swz(int pos) { return pos ^ ((pos >> 3) & 7); }

// ---------------- prepass: f32 [b][c][h][w] -> f16 h8 [b][cb][h][w] ----------------
__global__ __launch_bounds__(256) void pack_kernel(
    const float* __restrict__ in1, const float* __restrict__ in2,
    h8_t* __restrict__ ws1, h8_t* __restrict__ ws2) {
  const int t = blockIdx.x * 256 + threadIdx.x;   // [0, 2*NGRAN_)
  const int which = (t >= NGRAN_) ? 1 : 0;
  const int g = t - which * NGRAN_;
  const float* src = which ? in2 : in1;
  h8_t* dst = which ? ws2 : ws1;

  const int w  = g & (W_ - 1);
  const int h  = (g >> 7) % H_;
  const int cb = (g / (H_ * W_)) & 31;
  const int b  = g / (32 * H_ * W_);

  const float* p = src + ((size_t)(b * C_ + 8 * cb) * H_ + h) * W_ + w;
  float f[8];
#pragma unroll
  for (int j = 0; j < 8; ++j) f[j] = p[(size_t)j * HW_];
  h8_t pk;
#pragma unroll
  for (int jj = 0; jj < 4; ++jj) {
    half2_t q = __builtin_amdgcn_cvt_pkrtz(f[2 * jj], f[2 * jj + 1]);
    pk[2 * jj]     = q.x;
    pk[2 * jj + 1] = q.y;
  }
  dst[g] = pk;
}

// ---------------- main: packed-f16 path ----------------
__global__ __launch_bounds__(256, 2) void corr_packed_kernel(
    const h8_t* __restrict__ ws1,
    const h8_t* __restrict__ ws2,
    float* __restrict__ out) {
  // 4 independent per-wave regions; no cross-wave sharing -> no __syncthreads
  __shared__ h8_t lds[4 * 2 * P2_];

  const int tid  = threadIdx.x;
  const int wid  = tid >> 6;         // wave -> which h of the 4
  const int lane = tid & 63;
  const int l    = lane & 15;        // w-lane: w0 = 8*l covers W=128
  const int q    = (lane >> 4) & 1;  // dx half: 0 -> dx 0..10, 1 -> dx 11..20
  const int gdy  = lane >> 5;        // dy sub-index within wave's pair

  // XCD-chunked swizzle: 2112 = 8 * 264; each XCD chunk = one batch image
  int bid = blockIdx.x;
  bid = (bid & 7) * (NBLK_ / 8) + (bid >> 3);
  const int dyb = bid % 11;
  const int hg  = (bid / 11) % 24;
  const int b   = bid / (11 * 24);
  const int h   = hg * 4 + wid;

  const int dy   = 2 * dyb + gdy;    // 0..21 (21 = pad, store-masked)
  const int w0   = 8 * l;
  const int rel0 = 20 * q;           // q=1 computes dx=10..20, stores 11..20

  float acc[8][11];
#pragma unroll
  for (int j = 0; j < 8; ++j)
#pragma unroll
    for (int i = 0; i < 11; ++i) acc[j][i] = 0.f;

  const int wbase   = wid * (2 * P2_);
  const int ldsbase = wbase + gdy * P2_;

  for (int cb = 0; cb < 32; ++cb) {
    // ---- stage this wave's 2 dy rows x 168 pos (1 dwordx4 per pos) ----
#pragma unroll
    for (int s = lane; s < 2 * P2_; s += 64) {
      const int dyidx = (s >= P2_) ? 1 : 0;
      const int pos = s - P2_ * dyidx;
      const int h2 = h + 2 * (2 * dyb + dyidx) - MAXD_;
      const int w2 = pos - MAXD_;
      const bool v = ((unsigned)h2 < (unsigned)H_) && ((unsigned)w2 < (unsigned)W_);
      h8_t pk;
#pragma unroll
      for (int j = 0; j < 8; ++j) pk[j] = (__fp16)0.f;
      if (v) pk = ws2[((size_t)(b * 32 + cb) * H_ + h2) * W_ + w2];
      lds[wbase + dyidx * P2_ + swz(pos)] = pk;
    }

    // ---- A fragments: 8 consecutive w granules, no conversion ----
    const h8_t* ag = ws1 + ((size_t)(b * 32 + cb) * H_ + h) * W_ + w0;
    h8_t a8[8];
#pragma unroll
    for (int j = 0; j < 8; ++j) a8[j] = ag[j];

    // ---- preload 8-position register window (slot = rel & 7) ----
    // (in-order DS per wave: these reads see this chunk's writes, no barrier)
    h8_t wv[8];
#pragma unroll
    for (int k = 0; k < 8; ++k)
      wv[k] = lds[ldsbase + swz(w0 + rel0 + k)];

    // ---- 11 dx steps: 32 dot2 each, slide window by 2 ----
#pragma unroll
    for (int i = 0; i < 11; ++i) {
#pragma unroll
      for (int j = 0; j < 8; ++j) {
        const h8_t wj = wv[(2 * i + j) & 7];
        const h8_t aj = a8[j];
#pragma unroll
        for (int jj = 0; jj < 4; ++jj) {
          half2_t bb, aa;
          bb.x = wj[2 * jj];
          bb.y = wj[2 * jj + 1];
          aa.x = aj[2 * jj];
          aa.y = aj[2 * jj + 1];
          acc[j][i] = fdot2f(aa, bb, acc[j][i]);
        }
      }
      if (i < 10) {
        wv[(2 * i + 8) & 7] = lds[ldsbase + swz(w0 + rel0 + 2 * i + 8)];
        wv[(2 * i + 9) & 7] = lds[ldsbase + swz(w0 + rel0 + 2 * i + 9)];
      }
    }
  }

  // ---- epilogue ----
  if (dy < PATCH_) {
    const float s = 1.f / (float)C_;
#pragma unroll
    for (int i = 0; i < 11; ++i) {
      if (q && i == 0) continue;          // q=1's i=0 (dx=10) is duplicate work
      const int dx = 10 * q + i;
      float* ob = out + ((size_t)(b * (PATCH_ * PATCH_) + dy * PATCH_ + dx) * H_ + h) * W_ + w0;
      f4_t v0, v1;
#pragma unroll
      for (int j = 0; j < 4; ++j) {
        float x = acc[j][i] * s;
        v0[j] = (x >= 0.f) ? x : 0.1f * x;
        float y = acc[j + 4][i] * s;
        v1[j] = (y >= 0.f) ? y : 0.1f * y;
      }
      *(f4_t*)ob = v0;
      *(f4_t*)(ob + 4) = v1;
    }
  }
}

// ---------------- fallback (round-6 verified): f32 inputs, in-loop cvt ----------------
__global__ __launch_bounds__(256, 2) void corr_kernel(
    const float* __restrict__ in1,
    const float* __restrict__ in2,
    float* __restrict__ out) {
  __shared__ h8_t lds[4 * 2 * P2_];

  const int tid  = threadIdx.x;
  const int wid  = tid >> 6;
  const int lane = tid & 63;
  const int l    = lane & 15;
  const int q    = (lane >> 4) & 1;
  const int gdy  = lane >> 5;

  int bid = blockIdx.x;
  bid = (bid & 7) * (NBLK_ / 8) + (bid >> 3);
  const int dyb = bid % 11;
  const int hg  = (bid / 11) % 24;
  const int b   = bid / (11 * 24);
  const int h   = hg * 4 + wid;

  const int dy   = 2 * dyb + gdy;
  const int w0   = 8 * l;
  const int rel0 = 20 * q;

  float acc[8][11];
#pragma unroll
  for (int j = 0; j < 8; ++j)
#pragma unroll
    for (int i = 0; i < 11; ++i) acc[j][i] = 0.f;

  const int wbase   = wid * (2 * P2_);
  const int ldsbase = wbase + gdy * P2_;

  for (int c0 = 0; c0 < C_; c0 += 8) {
#pragma unroll
    for (int s = lane; s < 2 * P2_; s += 64) {
      const int dyidx = (s >= P2_) ? 1 : 0;
      const int pos = s - P2_ * dyidx;
      const int h2 = h + 2 * (2 * dyb + dyidx) - MAXD_;
      const int w2 = pos - MAXD_;
      const bool v = ((unsigned)h2 < (unsigned)H_) && ((unsigned)w2 < (unsigned)W_);
      float f[8];
      if (v) {
        const float* bp = in2 + ((size_t)(b * C_ + c0) * H_ + h2) * W_ + w2;
#pragma unroll
        for (int j = 0; j < 8; ++j) f[j] = bp[(size_t)j * HW_];
      } else {
#pragma unroll
        for (int j = 0; j < 8; ++j) f[j] = 0.f;
      }
      h8_t pk;
#pragma unroll
      for (int jj = 0; jj < 4; ++jj) {
        half2_t p2 = __builtin_amdgcn_cvt_pkrtz(f[2 * jj], f[2 * jj + 1]);
        pk[2 * jj]     = p2.x;
        pk[2 * jj + 1] = p2.y;
      }
      lds[wbase + dyidx * P2_ + swz(pos)] = pk;
    }

    const float* a_base = in1 + ((size_t)(b * C_ + c0) * H_ + h) * W_ + w0;
    half2_t a2[8][4];
#pragma unroll
    for (int jj = 0; jj < 4; ++jj) {
      f4_t lo0 = *(const f4_t*)(a_base + (size_t)(2 * jj) * HW_);
      f4_t lo1 = *(const f4_t*)(a_base + (size_t)(2 * jj) * HW_ + 4);
      f4_t hi0 = *(const f4_t*)(a_base + (size_t)(2 * jj + 1) * HW_);
      f4_t hi1 = *(const f4_t*)(a_base + (size_t)(2 * jj + 1) * HW_ + 4);
#pragma unroll
      for (int j = 0; j < 4; ++j) {
        a2[j][jj]     = __builtin_amdgcn_cvt_pkrtz(lo0[j], hi0[j]);
        a2[j + 4][jj] = __builtin_amdgcn_cvt_pkrtz(lo1[j], hi1[j]);
      }
    }

    h8_t wv[8];
#pragma unroll
    for (int k = 0; k < 8; ++k)
      wv[k] = lds[ldsbase + swz(w0 + rel0 + k)];

#pragma unroll
    for (int i = 0; i < 11; ++i) {
#pragma unroll
      for (int j = 0; j < 8; ++j) {
        const h8_t wj = wv[(2 * i + j) & 7];
#pragma unroll
        for (int jj = 0; jj < 4; ++jj) {
          half2_t bb;
          bb.x = wj[2 * jj];
          bb.y = wj[2 * jj + 1];
          acc[j][i] = fdot2f(a2[j][jj], bb, acc[j][i]);
        }
      }
      if (i < 10) {
        wv[(2 * i + 8) & 7] = lds[ldsbase + swz(w0 + rel0 + 2 * i + 8)];
        wv[(2 * i + 9) & 7] = lds[ldsbase + swz(w0 + rel0 + 2 * i + 9)];
      }
    }
  }

  if (dy < PATCH_) {
    const float s = 1.f / (float)C_;
#pragma unroll
    for (int i = 0; i < 11; ++i) {
      if (q && i == 0) continue;
      const int dx = 10 * q + i;
      float* ob = out + ((size_t)(b * (PATCH_ * PATCH_) + dy * PATCH_ + dx) * H_ + h) * W_ + w0;
      f4_t v0, v1;
#pragma unroll
      for (int j = 0; j < 4; ++j) {
        float x = acc[j][i] * s;
        v0[j] = (x >= 0.f) ? x : 0.1f * x;
        float y = acc[j + 4][i] * s;
        v1[j] = (y >= 0.f) ? y : 0.1f * y;
      }
      *(f4_t*)ob = v0;
      *(f4_t*)(ob + 4) = v1;
    }
  }
}

extern "C" void kernel_launch(void* const* d_in, const int* in_sizes, int n_in,
                              void* d_out, int out_size, void* d_ws, size_t ws_size,
                              hipStream_t stream) {
  (void)in_sizes; (void)n_in; (void)out_size;
  const float* in1 = (const float*)d_in[0];
  const float* in2 = (const float*)d_in[1];
  float* out = (float*)d_out;

  if (ws_size >= WS_NEED_) {
    h8_t* ws1 = (h8_t*)d_ws;
    h8_t* ws2 = ws1 + NGRAN_;
    pack_kernel<<<dim3(2 * NGRAN_ / 256), dim3(256), 0, stream>>>(in1, in2, ws1, ws2);
    corr_packed_kernel<<<dim3(NBLK_), dim3(256), 0, stream>>>(ws1, ws2, out);
  } else {
    corr_kernel<<<dim3(NBLK_), dim3(256), 0, stream>>>(in1, in2, out);
  }
}

// Round 8
// 299.739 us; speedup vs baseline: 4.1474x; 1.5984x over previous
//
#include <hip/hip_runtime.h>

#define B_ 8
#define C_ 256
#define H_ 96
#define W_ 128
#define HW_ (H_*W_)
#define PATCH_ 21
#define MAXD_ 20
#define WP_ 176                  // padded B width in granules (pos = w+2dx, 0..175)
#define NG1_ (B_*32*H_*W_)       // 3,145,728 A granules
#define NG2_ (B_*32*H_*WP_)     // 4,325,376 B granules
#define WS_NEED_ (((size_t)NG1_ + (size_t)NG2_) * 16)
#define NTASK_ (B_*H_*PATCH_*2)  // 32256 wave-tasks (2 w-halves)
#define NBLKM_ (NTASK_/4)        // 8064 blocks of 4 waves

typedef __fp16 half2_t __attribute__((ext_vector_type(2)));
typedef _Float16 f16x8 __attribute__((ext_vector_type(8)));
typedef float f32x4 __attribute__((ext_vector_type(4)));
typedef float f4_t __attribute__((ext_vector_type(4)));
typedef __fp16 h8_t __attribute__((ext_vector_type(8)));

// ---------------- prepass: f32 -> packed f16 granules ----------------
// ws1: A granules [b][cb][h][w]     (8 channels per granule)
// ws2: B granules [b][cb][h][wp]    wp in [0,176), value = in2[w2=wp-20] or 0
__global__ __launch_bounds__(256) void pack_kernel(
    const float* __restrict__ in1, const float* __restrict__ in2,
    f16x8* __restrict__ ws1, f16x8* __restrict__ ws2) {
  const int t = blockIdx.x * 256 + threadIdx.x;
  float f[8];
  if (t < NG1_) {
    const int w  = t & (W_ - 1);
    const int h  = (t >> 7) % H_;
    const int cb = (t / HW_) & 31;
    const int b  = t / (32 * HW_);
    const float* p = in1 + ((size_t)(b * C_ + 8 * cb) * H_ + h) * W_ + w;
#pragma unroll
    for (int j = 0; j < 8; ++j) f[j] = p[(size_t)j * HW_];
    f16x8 pk;
#pragma unroll
    for (int jj = 0; jj < 4; ++jj) {
      half2_t q = __builtin_amdgcn_cvt_pkrtz(f[2 * jj], f[2 * jj + 1]);
      pk[2 * jj]     = (_Float16)q.x;
      pk[2 * jj + 1] = (_Float16)q.y;
    }
    ws1[t] = pk;
  } else {
    const int g  = t - NG1_;
    const int wp = g % WP_;
    int rest = g / WP_;
    const int h  = rest % H_;
    rest /= H_;
    const int cb = rest & 31;
    const int b  = rest >> 5;
    const int w2 = wp - MAXD_;
    const bool v = (unsigned)w2 < (unsigned)W_;
#pragma unroll
    for (int j = 0; j < 8; ++j) f[j] = 0.f;
    if (v) {
      const float* p = in2 + ((size_t)(b * C_ + 8 * cb) * H_ + h) * W_ + w2;
#pragma unroll
      for (int j = 0; j < 8; ++j) f[j] = p[(size_t)j * HW_];
    }
    f16x8 pk;
#pragma unroll
    for (int jj = 0; jj < 4; ++jj) {
      half2_t q = __builtin_amdgcn_cvt_pkrtz(f[2 * jj], f[2 * jj + 1]);
      pk[2 * jj]     = (_Float16)q.x;
      pk[2 * jj + 1] = (_Float16)q.y;
    }
    ws2[g] = pk;
  }
}

// ---------------- main: banded-Gram MFMA ----------------
// task = (((b*96+h)*21+dy)*2 + thalf); wave computes out[b, dy, dx=0..20, h, w in 64-wide half]
__global__ __launch_bounds__(256) void corr_mfma(
    const f16x8* __restrict__ ws1,
    const f16x8* __restrict__ ws2,
    float* __restrict__ out) {
  const int wid  = threadIdx.x >> 6;
  const int lane = threadIdx.x & 63;
  const int n  = lane & 15;    // MFMA col (B free dim)
  const int kg = lane >> 4;    // k-group

  int blk = blockIdx.x;
  blk = (blk & 7) * (NBLKM_ / 8) + (blk >> 3);   // XCD-chunked (8064 = 8*1008)
  int task = blk * 4 + wid;
  const int thalf = task & 1; task >>= 1;
  const int dy = task % PATCH_; task /= PATCH_;
  const int h  = task % H_;
  const int b  = task / H_;
  const int t0 = thalf * 4;                      // tile base: w in [64*thalf, 64*thalf+64)
  const int h2 = h + 2 * dy - MAXD_;
  const bool rowok = (unsigned)h2 < (unsigned)H_;

  f32x4 acc[4][4];   // [tt][d]
#pragma unroll
  for (int tt = 0; tt < 4; ++tt)
#pragma unroll
    for (int d = 0; d < 4; ++d) acc[tt][d] = f32x4{0.f, 0.f, 0.f, 0.f};

  if (rowok) {
    // per-lane granule bases; chunk stride = 4 granule-planes
    const f16x8* pA = ws1 + (((size_t)(b * 32 + kg) * H_ + h) * W_ + t0 * 16 + n);
    const f16x8* pB = ws2 + (((size_t)(b * 32 + kg) * H_ + h2) * WP_ + t0 * 16 + n);
    for (int cb4 = 0; cb4 < 8; ++cb4) {
      f16x8 Af[4];
#pragma unroll
      for (int tt = 0; tt < 4; ++tt) Af[tt] = pA[tt * 16];
      f16x8 Bf[7];
#pragma unroll
      for (int u = 0; u < 7; ++u) Bf[u] = pB[u * 16];
#pragma unroll
      for (int tt = 0; tt < 4; ++tt)
#pragma unroll
        for (int d = 0; d < 4; ++d)
          acc[tt][d] = __builtin_amdgcn_mfma_f32_16x16x32_f16(
              Af[tt], Bf[tt + d], acc[tt][d], 0, 0, 0);
      pA += (size_t)4 * H_ * W_;
      pB += (size_t)4 * H_ * WP_;
    }
  }

  // epilogue: D[m][n] entry (tt,d,r): m=kg*4+r, w=16*(t0+tt)+m, 2dx=16d+n-m
  const float sc = 1.0f / (float)C_;
#pragma unroll
  for (int tt = 0; tt < 4; ++tt) {
#pragma unroll
    for (int r = 0; r < 4; ++r) {
      const int m = kg * 4 + r;
      const int w = (t0 + tt) * 16 + m;
#pragma unroll
      for (int d = 0; d < 4; ++d) {
        const int v2 = 16 * d + n - m;         // = 2*dx
        if (!(v2 & 1) && v2 >= 0 && v2 <= 40) {
          const int dx = v2 >> 1;
          float val = acc[tt][d][r] * sc;
          val = (val >= 0.f) ? val : 0.1f * val;
          out[(((size_t)b * (PATCH_ * PATCH_) + (size_t)(dy * PATCH_ + dx)) * H_ + h) * W_ + w] = val;
        }
      }
    }
  }
}

// ---------------- fallback (round-6 verified): f32 inputs, dot2 path ----------------
__device__ __forceinline__ float fdot2f(half2_t a, half2_t b, float c) {
  return __builtin_amdgcn_fdot2(a, b, c, false);
}
__device__ __forceinline__ int swz(int pos) { return pos ^ ((pos >> 3) & 7); }
#define P2_ 168
#define NBLK_ (B_*24*11)

__global__ __launch_bounds__(256, 2) void corr_kernel(
    const float* __restrict__ in1,
    const float* __restrict__ in2,
    float* __restrict__ out) {
  __shared__ h8_t lds[4 * 2 * P2_];
  const int tid  = threadIdx.x;
  const int wid  = tid >> 6;
  const int lane = tid & 63;
  const int l    = lane & 15;
  const int q    = (lane >> 4) & 1;
  const int gdy  = lane >> 5;
  int bid = blockIdx.x;
  bid = (bid & 7) * (NBLK_ / 8) + (bid >> 3);
  const int dyb = bid % 11;
  const int hg  = (bid / 11) % 24;
  const int b   = bid / (11 * 24);
  const int h   = hg * 4 + wid;
  const int dy   = 2 * dyb + gdy;
  const int w0   = 8 * l;
  const int rel0 = 20 * q;
  float acc[8][11];
#pragma unroll
  for (int j = 0; j < 8; ++j)
#pragma unroll
    for (int i = 0; i < 11; ++i) acc[j][i] = 0.f;
  const int wbase   = wid * (2 * P2_);
  const int ldsbase = wbase + gdy * P2_;
  for (int c0 = 0; c0 < C_; c0 += 8) {
#pragma unroll
    for (int s = lane; s < 2 * P2_; s += 64) {
      const int dyidx = (s >= P2_) ? 1 : 0;
      const int pos = s - P2_ * dyidx;
      const int h2 = h + 2 * (2 * dyb + dyidx) - MAXD_;
      const int w2 = pos - MAXD_;
      const bool v = ((unsigned)h2 < (unsigned)H_) && ((unsigned)w2 < (unsigned)W_);
      float f[8];
      if (v) {
        const float* bp = in2 + ((size_t)(b * C_ + c0) * H_ + h2) * W_ + w2;
#pragma unroll
        for (int j = 0; j < 8; ++j) f[j] = bp[(size_t)j * HW_];
      } else {
#pragma unroll
        for (int j = 0; j < 8; ++j) f[j] = 0.f;
      }
      h8_t pk;
#pragma unroll
      for (int jj = 0; jj < 4; ++jj) {
        half2_t p2 = __builtin_amdgcn_cvt_pkrtz(f[2 * jj], f[2 * jj + 1]);
        pk[2 * jj]     = p2.x;
        pk[2 * jj + 1] = p2.y;
      }
      lds[wbase + dyidx * P2_ + swz(pos)] = pk;
    }
    const float* a_base = in1 + ((size_t)(b * C_ + c0) * H_ + h) * W_ + w0;
    half2_t a2[8][4];
#pragma unroll
    for (int jj = 0; jj < 4; ++jj) {
      f4_t lo0 = *(const f4_t*)(a_base + (size_t)(2 * jj) * HW_);
      f4_t lo1 = *(const f4_t*)(a_base + (size_t)(2 * jj) * HW_ + 4);
      f4_t hi0 = *(const f4_t*)(a_base + (size_t)(2 * jj + 1) * HW_);
      f4_t hi1 = *(const f4_t*)(a_base + (size_t)(2 * jj + 1) * HW_ + 4);
#pragma unroll
      for (int j = 0; j < 4; ++j) {
        a2[j][jj]     = __builtin_amdgcn_cvt_pkrtz(lo0[j], hi0[j]);
        a2[j + 4][jj] = __builtin_amdgcn_cvt_pkrtz(lo1[j], hi1[j]);
      }
    }
    h8_t wv[8];
#pragma unroll
    for (int k = 0; k < 8; ++k)
      wv[k] = lds[ldsbase + swz(w0 + rel0 + k)];
#pragma unroll
    for (int i = 0; i < 11; ++i) {
#pragma unroll
      for (int j = 0; j < 8; ++j) {
        const h8_t wj = wv[(2 * i + j) & 7];
#pragma unroll
        for (int jj = 0; jj < 4; ++jj) {
          half2_t bb;
          bb.x = wj[2 * jj];
          bb.y = wj[2 * jj + 1];
          acc[j][i] = fdot2f(a2[j][jj], bb, acc[j][i]);
        }
      }
      if (i < 10) {
        wv[(2 * i + 8) & 7] = lds[ldsbase + swz(w0 + rel0 + 2 * i + 8)];
        wv[(2 * i + 9) & 7] = lds[ldsbase + swz(w0 + rel0 + 2 * i + 9)];
      }
    }
  }
  if (dy < PATCH_) {
    const float s = 1.f / (float)C_;
#pragma unroll
    for (int i = 0; i < 11; ++i) {
      if (q && i == 0) continue;
      const int dx = 10 * q + i;
      float* ob = out + ((size_t)(b * (PATCH_ * PATCH_) + dy * PATCH_ + dx) * H_ + h) * W_ + w0;
      f4_t v0, v1;
#pragma unroll
      for (int j = 0; j < 4; ++j) {
        float x = acc[j][i] * s;
        v0[j] = (x >= 0.f) ? x : 0.1f * x;
        float y = acc[j + 4][i] * s;
        v1[j] = (y >= 0.f) ? y : 0.1f * y;
      }
      *(f4_t*)ob = v0;
      *(f4_t*)(ob + 4) = v1;
    }
  }
}

extern "C" void kernel_launch(void* const* d_in, const int* in_sizes, int n_in,
                              void* d_out, int out_size, void* d_ws, size_t ws_size,
                              hipStream_t stream) {
  (void)in_sizes; (void)n_in; (void)out_size;
  const float* in1 = (const float*)d_in[0];
  const float* in2 = (const float*)d_in[1];
  float* out = (float*)d_out;

  if (ws_size >= WS_NEED_) {
    f16x8* ws1 = (f16x8*)d_ws;
    f16x8* ws2 = ws1 + NG1_;
    pack_kernel<<<dim3((NG1_ + NG2_) / 256), dim3(256), 0, stream>>>(in1, in2, ws1, ws2);
    corr_mfma<<<dim3(NBLKM_), dim3(256), 0, stream>>>(ws1, ws2, out);
  } else {
    corr_kernel<<<dim3(NBLK_), dim3(256), 0, stream>>>(in1, in2, out);
  }
}